// Round 4
// baseline (1176.762 us; speedup 1.0000x reference)
//
#include <hip/hip_runtime.h>

// NetG: seq2seq GRU (enc GRU -> +noise -> dec GRU -> FC head)
// B=512, T=256, H=256, D=3.
//
// R16 = lean-wave restructure of the proven R12 step.
//   R15 post-mortem: epilogue is column-parallel (per-lane work independent
//   of NB) -> NB-shrink moved nothing. Per-active-CU counters show MFMA 44%
//   + VALU 52% = serialized phases; 2 lockstep waves/SIMD (forced by the
//   256-reg weight-resident waves: 8 waves fill the 2048-reg pool) cannot
//   overlap them or hide latency.
//   Fix: make waves LEAN so 4 waves/SIMD fit and TLP hides latency:
//     - 32 blocks x 1024 thr (16 waves); each wave owns ONE hidden tile
//       (ht = wave id) x 3 gates. 16 batches/block, no pad columns.
//     - NO resident weight registers: all 3 gates x 8 k streamed per step
//       as b128 loads from a pre-packed bf16 fragment buffer (prep_wr packs
//       r,z,n; fragment-order, lane-contiguous). L2 traffic 384KB/block/step
//       = ~770 B/cyc/XCD at 4 blocks/XCD - well under the L2 ceiling.
//     - __launch_bounds__(1024, 4) caps regs at 128/wave -> 16 waves/CU.
//     - LDS: h double buffer (16KB) + x slots (33KB) = 49KB.
// Frozen from R6..R12: fp32 register h carry (exact), bf16 GEMM operands,
// fragment-order h LDS layout (woff/bbase pair), x staged in LDS with the
// decoder shift baked in + bias-column trick (q==0 A-lanes carry x/bias),
// native v_exp gates, interleaved epilogue -> x-step MFMA re-init tail,
// one barrier per step.

#define B_TOT 512
#define T_LEN 256
#define HID 256
#define NBATCH 16
#define NTHREADS 1024
#define NBLK 32

// LDS partition (units: shorts)
#define H_OFF 0                // 2 x 4096
#define X_OFF 8192             // 257 x 64 = 16448
#define SMEM_SHORTS (X_OFF + 257 * 64)      // 24640
#define SMEM_BYTES  (SMEM_SHORTS * 2)       // 49280 B

#define XT 64
#define XSLOTS (T_LEN + 1)
#define HBUF (NBATCH * HID)

// packed weight fragment buffer: [gate 0..2][ht 0..15][k 0..7][lane 0..63][8]
#define WRFRAG_SHORTS (3 * 16 * 8 * 64 * 8)   // 196608 shorts = 384 KB

typedef __attribute__((ext_vector_type(4))) float f32x4;
typedef __attribute__((ext_vector_type(8))) short shortx8;
typedef __attribute__((ext_vector_type(4))) short i16x4;
typedef __attribute__((ext_vector_type(4))) unsigned short ushortx4;
typedef __attribute__((ext_vector_type(8))) unsigned short ushortx8;

#if __has_builtin(__builtin_amdgcn_mfma_f32_16x16x16_bf16)
#define HAVE_K16 1
#define MFMA_X(A, B, C) __builtin_amdgcn_mfma_f32_16x16x16_bf16((A), (B), (C), 0, 0, 0)
#elif __has_builtin(__builtin_amdgcn_mfma_f32_16x16x16bf16_1k)
#define HAVE_K16 1
#define MFMA_X(A, B, C) __builtin_amdgcn_mfma_f32_16x16x16bf16_1k((A), (B), (C), 0, 0, 0)
#else
#define HAVE_K16 0
#endif

__device__ __forceinline__ unsigned short f2bf(float x) {
    unsigned u = __float_as_uint(x);
    u += 0x7FFF + ((u >> 16) & 1);   // RNE
    return (unsigned short)(u >> 16);
}
__device__ __forceinline__ float bf2f(unsigned short s) {
    return __uint_as_float(((unsigned)s) << 16);
}
__device__ __forceinline__ float fastrcp(float x) {
#if __has_builtin(__builtin_amdgcn_rcpf)
    return __builtin_amdgcn_rcpf(x);
#else
    return 1.0f / x;
#endif
}
__device__ __forceinline__ float exp2raw(float y) {
#if __has_builtin(__builtin_amdgcn_exp2f)
    return __builtin_amdgcn_exp2f(y);
#else
    return __expf(y * 0.69314718056f);
#endif
}
__device__ __forceinline__ float sigmoid_(float x) {
    return fastrcp(1.0f + exp2raw(x * -1.44269504f));
}
__device__ __forceinline__ float tanh_(float x) {
    return 2.0f * fastrcp(1.0f + exp2raw(x * -2.88539008f)) - 1.0f;
}

// Pack ALL of W_hh (gates r,z,n; k=0..7) into per-lane fragment layout:
//   dst[(((gate*16+ht)*8+k)*64+lane)*8 + j] =
//     bf16( W[gate*256 + ht*16 + (lane&15)][k*32 + (lane>>4)*8 + j] )
// One thread per fragment-lane (writes 8 shorts). 24576 frag-lanes per GRU.
__global__ __launch_bounds__(256) void prep_wr(
    const float* __restrict__ Whh_enc, const float* __restrict__ Whh_dec,
    unsigned short* __restrict__ wr_enc, unsigned short* __restrict__ wr_dec)
{
    int idx = blockIdx.x * 256 + threadIdx.x;    // 0..24575
    int gru = blockIdx.y;
    int lane = idx & 63;
    int k  = (idx >> 6) & 7;
    int ht = (idx >> 9) & 15;
    int gate = idx >> 13;                        // 0..2
    const float* W = gru ? Whh_dec : Whh_enc;
    unsigned short* dst = gru ? wr_dec : wr_enc;
    int row = gate * 256 + ht * 16 + (lane & 15);
    int col = k * 32 + (lane >> 4) * 8;
    const float* src = W + (size_t)row * 256 + col;
    ushortx8 v;
    #pragma unroll
    for (int j = 0; j < 8; ++j) v[j] = f2bf(src[j]);
    *(ushortx8*)(dst + (size_t)idx * 8) = v;
}

template<int IS_DEC>
__global__ __launch_bounds__(NTHREADS, 4) void gru_persistent(
    const float* __restrict__ X,       // [512][256][3]
    const float* __restrict__ W_ih,    // [768][3]
    const float* __restrict__ b_ih,    // [768]
    const float* __restrict__ b_hh,    // [768]
    const unsigned short* __restrict__ Wr, // packed frags (prep_wr), 384 KB
    const float* __restrict__ h_in,    // dec: [512][256] fp32; enc: null
    const float* __restrict__ noise,   // dec: [512][256]; enc: null
    float* __restrict__ h_out,         // enc: [512][256] fp32; dec: null
    unsigned short* __restrict__ Yout) // dec: [32][256][16][256] bf16
{
    extern __shared__ unsigned short smem[];
    unsigned short* shH = smem + H_OFF;
    unsigned short* shX = smem + X_OFF;

    const int tid  = threadIdx.x;
    const int g    = blockIdx.x;
    const int w    = tid >> 6;        // wave 0..15; owns hidden tile ht = w
    const int lane = tid & 63;
    const int c    = lane & 15;
    const int q    = lane >> 4;
    const int ht   = w;

    // ---- stage X into LDS (bf16, shift baked in; slot t = x for step t) ----
    for (int idx = tid; idx < NBATCH * XSLOTS; idx += NTHREADS) {
        int t = idx >> 4, cc = idx & 15;
        int ts = IS_DEC ? (t - 1) : t;
        float x0 = 0.0f, x1 = 0.0f, x2 = 0.0f;
        if (ts >= 0 && ts < T_LEN) {
            const float* xp = X + ((size_t)(g * NBATCH + cc) * T_LEN + ts) * 3;
            x0 = xp[0]; x1 = xp[1]; x2 = xp[2];
        }
        ushortx4 v = {f2bf(x0), f2bf(x1), f2bf(x2), (unsigned short)0x3F80};
        *(ushortx4*)&shX[t * XT + cc * 4] = v;
    }

    // ---- x/bias A-frags (q==0 lanes carry data; others MUST be zero) ----
#if HAVE_K16
    i16x4 ax[3];
#else
    shortx8 ax[3];
#endif
    {
        int rr_ = ht * 16 + c;
        int rowr = rr_, rowz = 256 + rr_, rown = 512 + rr_;
        short r0 = 0, r1 = 0, r2 = 0, r3 = 0, z0 = 0, z1 = 0, z2 = 0, z3 = 0;
        short n0 = 0, n1 = 0, n2 = 0, n3 = 0;
        if (q == 0) {
            r0 = (short)f2bf(W_ih[rowr * 3 + 0]);
            r1 = (short)f2bf(W_ih[rowr * 3 + 1]);
            r2 = (short)f2bf(W_ih[rowr * 3 + 2]);
            r3 = (short)f2bf(b_ih[rowr] + b_hh[rowr]);
            z0 = (short)f2bf(W_ih[rowz * 3 + 0]);
            z1 = (short)f2bf(W_ih[rowz * 3 + 1]);
            z2 = (short)f2bf(W_ih[rowz * 3 + 2]);
            z3 = (short)f2bf(b_ih[rowz] + b_hh[rowz]);
            n0 = (short)f2bf(W_ih[rown * 3 + 0]);
            n1 = (short)f2bf(W_ih[rown * 3 + 1]);
            n2 = (short)f2bf(W_ih[rown * 3 + 2]);
            n3 = (short)f2bf(b_ih[rown]);
        }
#if HAVE_K16
        ax[0] = i16x4{r0, r1, r2, r3};
        ax[1] = i16x4{z0, z1, z2, z3};
        ax[2] = i16x4{n0, n1, n2, n3};
#else
        ax[0] = shortx8{r0, r1, r2, r3, 0, 0, 0, 0};
        ax[1] = shortx8{z0, z1, z2, z3, 0, 0, 0, 0};
        ax[2] = shortx8{n0, n1, n2, n3, 0, 0, 0, 0};
#endif
    }

    // ---- nh-bias register constants (b_hh n-gate, this lane's rows) ----
    f32x4 nhb = *(const f32x4*)(b_hh + 512 + ht * 16 + q * 4);

    // ---- epilogue offset (fragment-order), loop-invariant ----
    int woff;
    {
        int kk = ht >> 1;
        int qq = ((ht & 1) << 1) | (q >> 1);
        woff = ((kk * 4 + qq) * 16 + c) * 8 + (q & 1) * 4;
    }

    // ---- init h0: fp32 carry in regs; bf16 frag into buffer 0 ----
    f32x4 hold = {0.0f, 0.0f, 0.0f, 0.0f};
    if (IS_DEC) {
        int b = g * NBATCH + c;
        int dim0 = ht * 16 + q * 4;
        f32x4 h0 = *(const f32x4*)(h_in + (size_t)b * HID + dim0);
        f32x4 nz = *(const f32x4*)(noise + (size_t)b * HID + dim0);
        hold = h0 + nz;
    }
    {
        ushortx4 hb16 = {f2bf(hold[0]), f2bf(hold[1]), f2bf(hold[2]), f2bf(hold[3])};
        *(ushortx4*)&shH[woff] = hb16;   // 16 waves x full tile = full h0
    }

    // ---- incremental decoder Y pointer (step stride = 4096 shorts) ----
    unsigned short* yp = nullptr;
    if (IS_DEC)
        yp = Yout + ((size_t)g * T_LEN * NBATCH + c) * HID + ht * 16 + q * 4;

    __syncthreads();

    const f32x4 zc = {0.0f, 0.0f, 0.0f, 0.0f};

    // ---- x-step for t=0 (C = inline 0 initializes acc r/z/nx) ----
    f32x4 acc0, acc1, acc2, acc3;   // r, z, nh, nx
    {
#if HAVE_K16
        i16x4 bx = *(const i16x4*)&shX[c * 4];
        acc0 = MFMA_X(ax[0], bx, zc);
        acc1 = MFMA_X(ax[1], bx, zc);
        acc3 = MFMA_X(ax[2], bx, zc);
#else
        ushortx4 xv = *(const ushortx4*)&shX[c * 4];
        shortx8 bx = (q == 0)
            ? shortx8{(short)xv[0], (short)xv[1], (short)xv[2], (short)xv[3], 0, 0, 0, 0}
            : shortx8{0, 0, 0, 0, 0, 0, 0, 0};
        acc0 = __builtin_amdgcn_mfma_f32_16x16x32_bf16(ax[0], bx, zc, 0, 0, 0);
        acc1 = __builtin_amdgcn_mfma_f32_16x16x32_bf16(ax[1], bx, zc, 0, 0, 0);
        acc3 = __builtin_amdgcn_mfma_f32_16x16x32_bf16(ax[2], bx, zc, 0, 0, 0);
#endif
    }

    // lane-fragment weight stream pointers (k stride = 512 shorts)
    const unsigned short* gr = Wr + ((size_t)((0 * 16 + ht) * 8) * 64 + lane) * 8;
    const unsigned short* gz = Wr + ((size_t)((1 * 16 + ht) * 8) * 64 + lane) * 8;
    const unsigned short* gn = Wr + ((size_t)((2 * 16 + ht) * 8) * 64 + lane) * 8;

    const int bbase = q * 128 + c * 8;   // lane's B-frag base within a buffer
    int xidx = XT + c * 4;               // x slot for step t+1 (incremental)

    // ---- recurrence ----
    for (int t = 0; t < T_LEN; ++t) {
        const unsigned short* brow = shH + (t & 1) * HBUF + bbase;
        unsigned short* hn = shH + ((t + 1) & 1) * HBUF;

        acc2 = nhb;
        #pragma unroll
        for (int k = 0; k < 8; ++k) {
            shortx8 fr = *(const shortx8*)(gr + k * 512);
            shortx8 fz = *(const shortx8*)(gz + k * 512);
            shortx8 fn = *(const shortx8*)(gn + k * 512);
            shortx8 bf = *(const shortx8*)(brow + k * 512);
            acc0 = __builtin_amdgcn_mfma_f32_16x16x32_bf16(fr, bf, acc0, 0, 0, 0);
            acc1 = __builtin_amdgcn_mfma_f32_16x16x32_bf16(fz, bf, acc1, 0, 0, 0);
            acc2 = __builtin_amdgcn_mfma_f32_16x16x32_bf16(fn, bf, acc2, 0, 0, 0);
        }

        // bx for step t+1
#if HAVE_K16
        i16x4 bxn = *(const i16x4*)&shX[xidx];
#else
        ushortx4 xvn = *(const ushortx4*)&shX[xidx];
        shortx8 bxn = (q == 0)
            ? shortx8{(short)xvn[0], (short)xvn[1], (short)xvn[2], (short)xvn[3], 0, 0, 0, 0}
            : shortx8{0, 0, 0, 0, 0, 0, 0, 0};
#endif
        xidx += XT;

        // ---- epilogue (1 tile) ----
        f32x4 ho;
        #pragma unroll
        for (int r = 0; r < 4; ++r) {
            float rr = sigmoid_(acc0[r]);
            float zz = sigmoid_(acc1[r]);
            float nn = tanh_(acc3[r] + rr * acc2[r]);
            ho[r] = nn + zz * (hold[r] - nn);
        }
        hold = ho;
        ushortx4 hb16 = {f2bf(ho[0]), f2bf(ho[1]), f2bf(ho[2]), f2bf(ho[3])};
        *(ushortx4*)(hn + woff) = hb16;
        if (IS_DEC) {
            *(ushortx4*)yp = hb16;
            yp += NBATCH * HID;   // stride 4096 shorts per step
        }

        // x-step re-init for t+1 (independent MFMAs under the trans tail)
#if HAVE_K16
        acc0 = MFMA_X(ax[0], bxn, zc);
        acc1 = MFMA_X(ax[1], bxn, zc);
        acc3 = MFMA_X(ax[2], bxn, zc);
#else
        acc0 = __builtin_amdgcn_mfma_f32_16x16x32_bf16(ax[0], bxn, zc, 0, 0, 0);
        acc1 = __builtin_amdgcn_mfma_f32_16x16x32_bf16(ax[1], bxn, zc, 0, 0, 0);
        acc3 = __builtin_amdgcn_mfma_f32_16x16x32_bf16(ax[2], bxn, zc, 0, 0, 0);
#endif
        __syncthreads();
    }

    if (!IS_DEC) {
        // hand the decoder the EXACT fp32 final h
        int dim0 = ht * 16 + q * 4;
        *(f32x4*)(h_out + (size_t)(g * NBATCH + c) * HID + dim0) = hold;
    }
}

// out[b][t][d] = sum_h Y[g][t][b16][h] * W_fc[d][h] + b_fc[d]
__global__ __launch_bounds__(256) void proj_kernel(
    const unsigned short* __restrict__ Y, const float* __restrict__ W_fc,
    const float* __restrict__ b_fc, float* __restrict__ out)
{
    int row = blockIdx.x * 256 + threadIdx.x;  // ((g*T + t)*16 + b16)
    int b16 = row & 15;
    int gt = row >> 4;
    int t = gt & (T_LEN - 1);
    int g = gt >> 8;
    const unsigned short* y = Y + (size_t)row * HID;
    float a0 = b_fc[0], a1 = b_fc[1], a2 = b_fc[2];
    #pragma unroll 4
    for (int k8 = 0; k8 < 32; ++k8) {
        ushortx8 v = *(const ushortx8*)(y + k8 * 8);
        #pragma unroll
        for (int j = 0; j < 8; ++j) {
            float f = bf2f(v[j]);
            int k = k8 * 8 + j;
            a0 += f * W_fc[k];          // uniform -> scalar loads
            a1 += f * W_fc[256 + k];
            a2 += f * W_fc[512 + k];
        }
    }
    int batch = g * NBATCH + b16;
    float* o = out + ((size_t)batch * T_LEN + t) * 3;
    o[0] = a0; o[1] = a1; o[2] = a2;
}

extern "C" void kernel_launch(void* const* d_in, const int* in_sizes, int n_in,
                              void* d_out, int out_size, void* d_ws, size_t ws_size,
                              hipStream_t stream)
{
    const float* X_p      = (const float*)d_in[0];
    const float* X_f      = (const float*)d_in[1];
    const float* noise    = (const float*)d_in[2];
    const float* W_ih_enc = (const float*)d_in[3];
    const float* W_hh_enc = (const float*)d_in[4];
    const float* b_ih_enc = (const float*)d_in[5];
    const float* b_hh_enc = (const float*)d_in[6];
    const float* W_ih_dec = (const float*)d_in[7];
    const float* W_hh_dec = (const float*)d_in[8];
    const float* b_ih_dec = (const float*)d_in[9];
    const float* b_hh_dec = (const float*)d_in[10];
    const float* W_fc     = (const float*)d_in[11];
    const float* b_fc     = (const float*)d_in[12];

    (void)hipFuncSetAttribute((const void*)&gru_persistent<0>,
                              hipFuncAttributeMaxDynamicSharedMemorySize, SMEM_BYTES);
    (void)hipFuncSetAttribute((const void*)&gru_persistent<1>,
                              hipFuncAttributeMaxDynamicSharedMemorySize, SMEM_BYTES);

    // ws: [0,512K) h_enc fp32 | [512K,896K) Wr_enc | [896K,1280K) Wr_dec |
    //     [1280K, +67.1MB) decoder Y bf16
    float* h_enc = (float*)d_ws;
    unsigned short* wr_enc = (unsigned short*)((char*)d_ws + (512u << 10));
    unsigned short* wr_dec = (unsigned short*)((char*)d_ws + (896u << 10));
    unsigned short* Yws    = (unsigned short*)((char*)d_ws + (1280u << 10));

    hipLaunchKernelGGL(prep_wr, dim3(96, 2), dim3(256), 0, stream,
        W_hh_enc, W_hh_dec, wr_enc, wr_dec);

    hipLaunchKernelGGL((gru_persistent<0>), dim3(NBLK), dim3(NTHREADS), SMEM_BYTES, stream,
        X_p, W_ih_enc, b_ih_enc, b_hh_enc, wr_enc,
        (const float*)nullptr, (const float*)nullptr, h_enc,
        (unsigned short*)nullptr);

    hipLaunchKernelGGL((gru_persistent<1>), dim3(NBLK), dim3(NTHREADS), SMEM_BYTES, stream,
        X_f, W_ih_dec, b_ih_dec, b_hh_dec, wr_dec,
        h_enc, noise, (float*)nullptr, Yws);

    hipLaunchKernelGGL(proj_kernel, dim3((B_TOT * T_LEN) / 256), dim3(256), 0, stream,
        Yws, W_fc, b_fc, (float*)d_out);
}

// Round 5
// 806.802 us; speedup vs baseline: 1.4586x; 1.4586x over previous
//
#include <hip/hip_runtime.h>

// NetG: seq2seq GRU (enc GRU -> +noise -> dec GRU -> FC head)
// B=512, T=256, H=256, D=3.
//
// R17 = R12's resident-weight step reorganized for 4 waves/SIMD.
//   R16 post-mortem: streaming all weights from L2 = 384KB/step/CU over a
//   ~64B/cyc CU ingress port = ~6000 cyc/step -> 616us. Weights must stay
//   resident. R12's limiter was 256-reg waves (2/SIMD). Fix: ONE tile per
//   wave, 16 waves (1024 thr): z,n resident = 64 VGPRs, total ~120 ->
//   launch_bounds(1024,4) -> <=128 regs -> 16 waves/CU = 4/SIMD. Per-CU
//   work unchanged vs R12; doubled TLP covers the ~48% stall fraction R12
//   showed (3680 cyc/step vs ~1900 issue).
// Weight paths (R12-proven): gate r k=0..3 LDS frags (64KB), k=4..7
// global L2 prefetch (prep_wr, 64KB/step/CU, issued at step start and
// consumed after the LDS half); gates z,n in registers.
// Frozen from R6..R16: fp32 register h carry (exact), bf16 GEMM operands,
// fragment-order h LDS layout (woff/bbase pair), x staged in LDS with the
// decoder shift baked in + bias-column trick (q==0 A-lanes carry x/bias),
// native v_exp gates, interleaved epilogue -> x-step MFMA re-init tail,
// one barrier per step, incremental Y pointers.

#define B_TOT 512
#define T_LEN 256
#define HID 256
#define NBATCH 16
#define NTHREADS 1024
#define NBLK 32

// LDS partition (units: shorts)
#define WR_OFF 0               // gate-r k=0..3 frags: 16*4*64*8 = 32768
#define H_OFF  32768           // 2 x 4096
#define X_OFF  40960           // 257 x 64 = 16448
#define SMEM_SHORTS 57408
#define SMEM_BYTES  (SMEM_SHORTS * 2)   // 114816 B <= 160 KiB (1 block/CU)

#define XT 64
#define XSLOTS (T_LEN + 1)
#define HBUF (NBATCH * HID)

typedef __attribute__((ext_vector_type(4))) float f32x4;
typedef __attribute__((ext_vector_type(8))) short shortx8;
typedef __attribute__((ext_vector_type(4))) short i16x4;
typedef __attribute__((ext_vector_type(4))) unsigned short ushortx4;
typedef __attribute__((ext_vector_type(8))) unsigned short ushortx8;

#if __has_builtin(__builtin_amdgcn_mfma_f32_16x16x16_bf16)
#define HAVE_K16 1
#define MFMA_X(A, B, C) __builtin_amdgcn_mfma_f32_16x16x16_bf16((A), (B), (C), 0, 0, 0)
#elif __has_builtin(__builtin_amdgcn_mfma_f32_16x16x16bf16_1k)
#define HAVE_K16 1
#define MFMA_X(A, B, C) __builtin_amdgcn_mfma_f32_16x16x16bf16_1k((A), (B), (C), 0, 0, 0)
#else
#define HAVE_K16 0
#endif

__device__ __forceinline__ unsigned short f2bf(float x) {
    unsigned u = __float_as_uint(x);
    u += 0x7FFF + ((u >> 16) & 1);   // RNE
    return (unsigned short)(u >> 16);
}
__device__ __forceinline__ float bf2f(unsigned short s) {
    return __uint_as_float(((unsigned)s) << 16);
}
__device__ __forceinline__ float fastrcp(float x) {
#if __has_builtin(__builtin_amdgcn_rcpf)
    return __builtin_amdgcn_rcpf(x);
#else
    return 1.0f / x;
#endif
}
__device__ __forceinline__ float exp2raw(float y) {
#if __has_builtin(__builtin_amdgcn_exp2f)
    return __builtin_amdgcn_exp2f(y);
#else
    return __expf(y * 0.69314718056f);
#endif
}
__device__ __forceinline__ float sigmoid_(float x) {
    return fastrcp(1.0f + exp2raw(x * -1.44269504f));
}
__device__ __forceinline__ float tanh_(float x) {
    return 2.0f * fastrcp(1.0f + exp2raw(x * -2.88539008f)) - 1.0f;
}

// Pack gate-r (rows 0..255 of W_hh), K-half k=4..7, into per-lane fragment
// layout: dst[((ht*4+kk)*64+lane)*8+j] = bf16(W[ht*16+(lane&15)][(kk+4)*32+(lane>>4)*8+j])
__global__ __launch_bounds__(256) void prep_wr(
    const float* __restrict__ Whh_enc, const float* __restrict__ Whh_dec,
    unsigned short* __restrict__ wr_enc, unsigned short* __restrict__ wr_dec)
{
    int idx = blockIdx.x * 256 + threadIdx.x;    // 0..8191
    int gru = idx >> 12;
    int rem = idx & 4095;                        // (ht*4+kk)*64 + lane
    int lane = rem & 63;
    int kk = (rem >> 6) & 3;
    int ht = rem >> 8;
    const float* W = gru ? Whh_dec : Whh_enc;
    unsigned short* dst = gru ? wr_dec : wr_enc;
    int row = ht * 16 + (lane & 15);
    int col = (kk + 4) * 32 + (lane >> 4) * 8;
    const float* src = W + (size_t)row * 256 + col;
    ushortx8 v;
    #pragma unroll
    for (int j = 0; j < 8; ++j) v[j] = f2bf(src[j]);
    *(ushortx8*)(dst + (size_t)rem * 8) = v;
}

template<int IS_DEC>
__global__ __launch_bounds__(NTHREADS, 4) void gru_persistent(
    const float* __restrict__ X,       // [512][256][3]
    const float* __restrict__ W_hh,    // [768][256] gates r,z,n
    const float* __restrict__ W_ih,    // [768][3]
    const float* __restrict__ b_ih,    // [768]
    const float* __restrict__ b_hh,    // [768]
    const unsigned short* __restrict__ Wr4, // gate-r k=4..7 frags (prep_wr)
    const float* __restrict__ h_in,    // dec: [512][256] fp32; enc: null
    const float* __restrict__ noise,   // dec: [512][256]; enc: null
    float* __restrict__ h_out,         // enc: [512][256] fp32; dec: null
    unsigned short* __restrict__ Yout) // dec: [32][256][16][256] bf16
{
    extern __shared__ unsigned short smem[];
    unsigned short* shWr = smem + WR_OFF;
    unsigned short* shH  = smem + H_OFF;
    unsigned short* shX  = smem + X_OFF;

    const int tid  = threadIdx.x;
    const int g    = blockIdx.x;
    const int w    = tid >> 6;        // wave 0..15; owns hidden tile ht = w
    const int lane = tid & 63;
    const int c    = lane & 15;
    const int q    = lane >> 4;
    const int ht   = w;

    // ---- stage X into LDS (bf16, shift baked in; slot t = x for step t) ----
    for (int idx = tid; idx < NBATCH * XSLOTS; idx += NTHREADS) {
        int t = idx >> 4, cc = idx & 15;
        int ts = IS_DEC ? (t - 1) : t;
        float x0 = 0.0f, x1 = 0.0f, x2 = 0.0f;
        if (ts >= 0 && ts < T_LEN) {
            const float* xp = X + ((size_t)(g * NBATCH + cc) * T_LEN + ts) * 3;
            x0 = xp[0]; x1 = xp[1]; x2 = xp[2];
        }
        ushortx4 v = {f2bf(x0), f2bf(x1), f2bf(x2), (unsigned short)0x3F80};
        *(ushortx4*)&shX[t * XT + cc * 4] = v;
    }

    // ---- gate-r k=0..3 frags -> LDS (each wave stages its 1 tile) ----
    {
        int row = ht * 16 + c;                      // gate r
        const float* wp = W_hh + (size_t)row * 256 + q * 8;
        #pragma unroll
        for (int k = 0; k < 4; ++k) {
            const f32x4* p = (const f32x4*)(wp + k * 32);
            f32x4 f0 = p[0];
            f32x4 f1 = p[1];
            shortx8 a;
            a[0] = (short)f2bf(f0[0]); a[1] = (short)f2bf(f0[1]);
            a[2] = (short)f2bf(f0[2]); a[3] = (short)f2bf(f0[3]);
            a[4] = (short)f2bf(f1[0]); a[5] = (short)f2bf(f1[1]);
            a[6] = (short)f2bf(f1[2]); a[7] = (short)f2bf(f1[3]);
            *(shortx8*)&shWr[((ht * 4 + k) * 64 + lane) * 8] = a;
        }
    }

    // ---- gates z,n A-frags into registers (64 regs, resident) ----
    shortx8 Wf[2][8];   // [z|n][k]
    #pragma unroll
    for (int gg = 0; gg < 2; ++gg) {
        int row = (gg + 1) * 256 + ht * 16 + c;
        const float* wp = W_hh + (size_t)row * 256 + q * 8;
        #pragma unroll
        for (int k = 0; k < 8; ++k) {
            const f32x4* p = (const f32x4*)(wp + k * 32);
            f32x4 f0 = p[0];
            f32x4 f1 = p[1];
            shortx8 a;
            a[0] = (short)f2bf(f0[0]); a[1] = (short)f2bf(f0[1]);
            a[2] = (short)f2bf(f0[2]); a[3] = (short)f2bf(f0[3]);
            a[4] = (short)f2bf(f1[0]); a[5] = (short)f2bf(f1[1]);
            a[6] = (short)f2bf(f1[2]); a[7] = (short)f2bf(f1[3]);
            Wf[gg][k] = a;
        }
    }

    // ---- x/bias A-frags (q==0 lanes carry data; others MUST be zero) ----
#if HAVE_K16
    i16x4 ax[3];
#else
    shortx8 ax[3];
#endif
    {
        int rr_ = ht * 16 + c;
        int rowr = rr_, rowz = 256 + rr_, rown = 512 + rr_;
        short r0 = 0, r1 = 0, r2 = 0, r3 = 0, z0 = 0, z1 = 0, z2 = 0, z3 = 0;
        short n0 = 0, n1 = 0, n2 = 0, n3 = 0;
        if (q == 0) {
            r0 = (short)f2bf(W_ih[rowr * 3 + 0]);
            r1 = (short)f2bf(W_ih[rowr * 3 + 1]);
            r2 = (short)f2bf(W_ih[rowr * 3 + 2]);
            r3 = (short)f2bf(b_ih[rowr] + b_hh[rowr]);
            z0 = (short)f2bf(W_ih[rowz * 3 + 0]);
            z1 = (short)f2bf(W_ih[rowz * 3 + 1]);
            z2 = (short)f2bf(W_ih[rowz * 3 + 2]);
            z3 = (short)f2bf(b_ih[rowz] + b_hh[rowz]);
            n0 = (short)f2bf(W_ih[rown * 3 + 0]);
            n1 = (short)f2bf(W_ih[rown * 3 + 1]);
            n2 = (short)f2bf(W_ih[rown * 3 + 2]);
            n3 = (short)f2bf(b_ih[rown]);
        }
#if HAVE_K16
        ax[0] = i16x4{r0, r1, r2, r3};
        ax[1] = i16x4{z0, z1, z2, z3};
        ax[2] = i16x4{n0, n1, n2, n3};
#else
        ax[0] = shortx8{r0, r1, r2, r3, 0, 0, 0, 0};
        ax[1] = shortx8{z0, z1, z2, z3, 0, 0, 0, 0};
        ax[2] = shortx8{n0, n1, n2, n3, 0, 0, 0, 0};
#endif
    }

    // ---- nh-bias register constants (b_hh n-gate, this lane's rows) ----
    f32x4 nhb = *(const f32x4*)(b_hh + 512 + ht * 16 + q * 4);

    // ---- epilogue offset (fragment-order), loop-invariant ----
    int woff;
    {
        int kk = ht >> 1;
        int qq = ((ht & 1) << 1) | (q >> 1);
        woff = ((kk * 4 + qq) * 16 + c) * 8 + (q & 1) * 4;
    }

    // ---- init h0: fp32 carry in regs; bf16 frag into buffer 0 ----
    f32x4 hold = {0.0f, 0.0f, 0.0f, 0.0f};
    if (IS_DEC) {
        int b = g * NBATCH + c;
        int dim0 = ht * 16 + q * 4;
        f32x4 h0 = *(const f32x4*)(h_in + (size_t)b * HID + dim0);
        f32x4 nz = *(const f32x4*)(noise + (size_t)b * HID + dim0);
        hold = h0 + nz;
    }
    {
        ushortx4 hb16 = {f2bf(hold[0]), f2bf(hold[1]), f2bf(hold[2]), f2bf(hold[3])};
        *(ushortx4*)&shH[woff] = hb16;   // 16 waves x full tile = full h0
    }

    // ---- incremental decoder Y pointer (step stride = 4096 shorts) ----
    unsigned short* yp = nullptr;
    if (IS_DEC)
        yp = Yout + ((size_t)g * T_LEN * NBATCH + c) * HID + ht * 16 + q * 4;

    __syncthreads();

    const f32x4 zc = {0.0f, 0.0f, 0.0f, 0.0f};

    // ---- x-step for t=0 (C = inline 0 initializes acc r/z/nx) ----
    f32x4 acc0, acc1, acc2, acc3;   // r, z, nh, nx
    {
#if HAVE_K16
        i16x4 bx = *(const i16x4*)&shX[c * 4];
        acc0 = MFMA_X(ax[0], bx, zc);
        acc1 = MFMA_X(ax[1], bx, zc);
        acc3 = MFMA_X(ax[2], bx, zc);
#else
        ushortx4 xv = *(const ushortx4*)&shX[c * 4];
        shortx8 bx = (q == 0)
            ? shortx8{(short)xv[0], (short)xv[1], (short)xv[2], (short)xv[3], 0, 0, 0, 0}
            : shortx8{0, 0, 0, 0, 0, 0, 0, 0};
        acc0 = __builtin_amdgcn_mfma_f32_16x16x32_bf16(ax[0], bx, zc, 0, 0, 0);
        acc1 = __builtin_amdgcn_mfma_f32_16x16x32_bf16(ax[1], bx, zc, 0, 0, 0);
        acc3 = __builtin_amdgcn_mfma_f32_16x16x32_bf16(ax[2], bx, zc, 0, 0, 0);
#endif
    }

    const int bbase = q * 128 + c * 8;   // lane's B-frag base within a buffer
    const unsigned short* ab = shWr + ((size_t)(ht * 4) * 64 + lane) * 8;
    const unsigned short* gb = Wr4 + ((size_t)(ht * 4) * 64 + lane) * 8;

    int xidx = XT + c * 4;   // x slot for step t+1 (incremental)

    // ---- recurrence ----
    for (int t = 0; t < T_LEN; ++t) {
        const unsigned short* brow = shH + (t & 1) * HBUF + bbase;
        unsigned short* hn = shH + ((t + 1) & 1) * HBUF;

        // gate-r k=4..7 from global: issued at step start, consumed after
        // the LDS half (~500 cyc of MFMA slack — R6/R12's proven timing)
        shortx8 gr[4];
        #pragma unroll
        for (int kk = 0; kk < 4; ++kk)
            gr[kk] = *(const shortx8*)(gb + kk * 512);

        // n-gate hidden accumulator starts from the b_hh bias constants
        acc2 = nhb;

        // k=0..3: gate-r from LDS
        #pragma unroll
        for (int k = 0; k < 4; ++k) {
            shortx8 bf = *(const shortx8*)(brow + k * 512);
            shortx8 ar = *(const shortx8*)(ab + k * 512);
            acc0 = __builtin_amdgcn_mfma_f32_16x16x32_bf16(ar,       bf, acc0, 0, 0, 0);
            acc1 = __builtin_amdgcn_mfma_f32_16x16x32_bf16(Wf[0][k], bf, acc1, 0, 0, 0);
            acc2 = __builtin_amdgcn_mfma_f32_16x16x32_bf16(Wf[1][k], bf, acc2, 0, 0, 0);
        }
        // k=4..7: gate-r from the global prefetch
        #pragma unroll
        for (int k = 4; k < 8; ++k) {
            shortx8 bf = *(const shortx8*)(brow + k * 512);
            acc0 = __builtin_amdgcn_mfma_f32_16x16x32_bf16(gr[k - 4], bf, acc0, 0, 0, 0);
            acc1 = __builtin_amdgcn_mfma_f32_16x16x32_bf16(Wf[0][k],  bf, acc1, 0, 0, 0);
            acc2 = __builtin_amdgcn_mfma_f32_16x16x32_bf16(Wf[1][k],  bf, acc2, 0, 0, 0);
        }

        // bx for step t+1
#if HAVE_K16
        i16x4 bxn = *(const i16x4*)&shX[xidx];
#else
        ushortx4 xvn = *(const ushortx4*)&shX[xidx];
        shortx8 bxn = (q == 0)
            ? shortx8{(short)xvn[0], (short)xvn[1], (short)xvn[2], (short)xvn[3], 0, 0, 0, 0}
            : shortx8{0, 0, 0, 0, 0, 0, 0, 0};
#endif
        xidx += XT;

        // ---- epilogue (1 tile) ----
        f32x4 ho;
        #pragma unroll
        for (int r = 0; r < 4; ++r) {
            float rr = sigmoid_(acc0[r]);
            float zz = sigmoid_(acc1[r]);
            float nn = tanh_(acc3[r] + rr * acc2[r]);
            ho[r] = nn + zz * (hold[r] - nn);
        }
        hold = ho;
        ushortx4 hb16 = {f2bf(ho[0]), f2bf(ho[1]), f2bf(ho[2]), f2bf(ho[3])};
        *(ushortx4*)(hn + woff) = hb16;
        if (IS_DEC) {
            *(ushortx4*)yp = hb16;
            yp += NBATCH * HID;   // stride 4096 shorts per step
        }

        // x-step re-init for t+1 (independent MFMAs under the trans tail)
#if HAVE_K16
        acc0 = MFMA_X(ax[0], bxn, zc);
        acc1 = MFMA_X(ax[1], bxn, zc);
        acc3 = MFMA_X(ax[2], bxn, zc);
#else
        acc0 = __builtin_amdgcn_mfma_f32_16x16x32_bf16(ax[0], bxn, zc, 0, 0, 0);
        acc1 = __builtin_amdgcn_mfma_f32_16x16x32_bf16(ax[1], bxn, zc, 0, 0, 0);
        acc3 = __builtin_amdgcn_mfma_f32_16x16x32_bf16(ax[2], bxn, zc, 0, 0, 0);
#endif
        __syncthreads();
    }

    if (!IS_DEC) {
        // hand the decoder the EXACT fp32 final h
        int dim0 = ht * 16 + q * 4;
        *(f32x4*)(h_out + (size_t)(g * NBATCH + c) * HID + dim0) = hold;
    }
}

// out[b][t][d] = sum_h Y[g][t][b16][h] * W_fc[d][h] + b_fc[d]
__global__ __launch_bounds__(256) void proj_kernel(
    const unsigned short* __restrict__ Y, const float* __restrict__ W_fc,
    const float* __restrict__ b_fc, float* __restrict__ out)
{
    int row = blockIdx.x * 256 + threadIdx.x;  // ((g*T + t)*16 + b16)
    int b16 = row & 15;
    int gt = row >> 4;
    int t = gt & (T_LEN - 1);
    int g = gt >> 8;
    const unsigned short* y = Y + (size_t)row * HID;
    float a0 = b_fc[0], a1 = b_fc[1], a2 = b_fc[2];
    #pragma unroll 4
    for (int k8 = 0; k8 < 32; ++k8) {
        ushortx8 v = *(const ushortx8*)(y + k8 * 8);
        #pragma unroll
        for (int j = 0; j < 8; ++j) {
            float f = bf2f(v[j]);
            int k = k8 * 8 + j;
            a0 += f * W_fc[k];          // uniform -> scalar loads
            a1 += f * W_fc[256 + k];
            a2 += f * W_fc[512 + k];
        }
    }
    int batch = g * NBATCH + b16;
    float* o = out + ((size_t)batch * T_LEN + t) * 3;
    o[0] = a0; o[1] = a1; o[2] = a2;
}

extern "C" void kernel_launch(void* const* d_in, const int* in_sizes, int n_in,
                              void* d_out, int out_size, void* d_ws, size_t ws_size,
                              hipStream_t stream)
{
    const float* X_p      = (const float*)d_in[0];
    const float* X_f      = (const float*)d_in[1];
    const float* noise    = (const float*)d_in[2];
    const float* W_ih_enc = (const float*)d_in[3];
    const float* W_hh_enc = (const float*)d_in[4];
    const float* b_ih_enc = (const float*)d_in[5];
    const float* b_hh_enc = (const float*)d_in[6];
    const float* W_ih_dec = (const float*)d_in[7];
    const float* W_hh_dec = (const float*)d_in[8];
    const float* b_ih_dec = (const float*)d_in[9];
    const float* b_hh_dec = (const float*)d_in[10];
    const float* W_fc     = (const float*)d_in[11];
    const float* b_fc     = (const float*)d_in[12];

    // allow >64 KiB dynamic LDS (idempotent; host-side, graph-capture safe)
    (void)hipFuncSetAttribute((const void*)&gru_persistent<0>,
                              hipFuncAttributeMaxDynamicSharedMemorySize, SMEM_BYTES);
    (void)hipFuncSetAttribute((const void*)&gru_persistent<1>,
                              hipFuncAttributeMaxDynamicSharedMemorySize, SMEM_BYTES);

    // ws: [0,512K) h_enc fp32 | [512K,576K) Wr_enc | [576K,640K) Wr_dec |
    //     [640K, +67.1MB) decoder Y bf16
    float* h_enc = (float*)d_ws;
    unsigned short* wr_enc = (unsigned short*)((char*)d_ws + (512u << 10));
    unsigned short* wr_dec = (unsigned short*)((char*)d_ws + (576u << 10));
    unsigned short* Yws    = (unsigned short*)((char*)d_ws + (640u << 10));

    hipLaunchKernelGGL(prep_wr, dim3(32), dim3(256), 0, stream,
        W_hh_enc, W_hh_dec, wr_enc, wr_dec);

    hipLaunchKernelGGL((gru_persistent<0>), dim3(NBLK), dim3(NTHREADS), SMEM_BYTES, stream,
        X_p, W_hh_enc, W_ih_enc, b_ih_enc, b_hh_enc, wr_enc,
        (const float*)nullptr, (const float*)nullptr, h_enc,
        (unsigned short*)nullptr);

    hipLaunchKernelGGL((gru_persistent<1>), dim3(NBLK), dim3(NTHREADS), SMEM_BYTES, stream,
        X_f, W_hh_dec, W_ih_dec, b_ih_dec, b_hh_dec, wr_dec,
        h_enc, noise, (float*)nullptr, Yws);

    hipLaunchKernelGGL(proj_kernel, dim3((B_TOT * T_LEN) / 256), dim3(256), 0, stream,
        Yws, W_fc, b_fc, (float*)d_out);
}